// Round 7
// baseline (433.816 us; speedup 1.0000x reference)
//
#include <hip/hip_runtime.h>
#include <math.h>

#define D_DIM 4096
#define ROWS_PER_WG 16

typedef float v2f __attribute__((ext_vector_type(2)));

// ---- packed-f32 butterfly primitives (VOP3P) ----
__device__ __forceinline__ v2f bfly0(v2f a) {
    v2f d;
    asm("v_pk_add_f32 %0, %1, %2 op_sel:[0,1] op_sel_hi:[0,1] neg_hi:[0,1]"
        : "=v"(d) : "v"(a), "v"(a));
    return d;
}
__device__ __forceinline__ v2f pkadd(v2f a, v2f b) {
    v2f d; asm("v_pk_add_f32 %0, %1, %2" : "=v"(d) : "v"(a), "v"(b)); return d;
}
__device__ __forceinline__ v2f pksub(v2f a, v2f b) {
    v2f d; asm("v_pk_add_f32 %0, %1, %2 neg_lo:[0,1] neg_hi:[0,1]" : "=v"(d) : "v"(a), "v"(b)); return d;
}
__device__ __forceinline__ v2f pkmul(v2f a, v2f b) {
    v2f d; asm("v_pk_mul_f32 %0, %1, %2" : "=v"(d) : "v"(a), "v"(b)); return d;
}

// In-register FWHT over 6 bits: 64 values as 32 packed v2f.
__device__ __forceinline__ void radix64(v2f w[32]) {
#pragma unroll
    for (int p = 0; p < 32; ++p) w[p] = bfly0(w[p]);
#pragma unroll
    for (int s = 0; s < 5; ++s) {
        const int d = 1 << s;
#pragma unroll
        for (int p = 0; p < 32; ++p) {
            if (!(p & d)) {
                const v2f a = w[p];
                const v2f b = w[p + d];
                w[p]     = pkadd(a, b);
                w[p + d] = pksub(a, b);
            }
        }
    }
}

// async global->LDS, 16 B per lane; LDS dest = uniform base + lane*16.
__device__ __forceinline__ void gload_lds16(const float* g, float* lp) {
    __builtin_amdgcn_global_load_lds(
        (const __attribute__((address_space(1))) void*)g,
        (__attribute__((address_space(3))) void*)lp, 16, 0, 0);
}

// LDS ops as inline asm: invisible to the compiler's LDS-DMA alias analysis,
// so it cannot insert conservative vmcnt drains that kill the glds prefetch.
__device__ __forceinline__ float4 ds_read128(unsigned byte_addr) {
    float4 d;
    asm volatile("ds_read_b128 %0, %1" : "=v"(d) : "v"(byte_addr));
    return d;
}
__device__ __forceinline__ void ds_write32(unsigned byte_addr, float val) {
    asm volatile("ds_write_b32 %0, %1" : : "v"(byte_addr), "v"(val));
}
__device__ __forceinline__ void wait_lgkm0() {
    asm volatile("s_waitcnt lgkmcnt(0)" ::: "memory");
    __builtin_amdgcn_sched_barrier(0);
}

// opaque pointer copy: blocks LICM/CSE from persisting per-row reloads.
__device__ __forceinline__ const float* launder_ptr(const float* p) {
    asm volatile("" : "+s"(p));
    return p;
}

// u_perm[l*64 + m] = u[e]/64, e = (l>>2)*256 + m*4 + (l&3)  (B-layout).
__global__ void compute_u_kernel(const float* __restrict__ g_mu,
                                 const float* __restrict__ g_rho,
                                 const float* __restrict__ eps,
                                 float* __restrict__ u_perm) {
    const int j = blockIdx.x * blockDim.x + threadIdx.x;
    if (j < D_DIM) {
        const int e = ((j >> 8) << 8) | ((j & 63) << 2) | ((j >> 6) & 3);
        const float r = g_rho[e];
        const float sp = (r > 20.0f) ? r : log1pf(expf(r));
        u_perm[j] = (g_mu[e] + sp * eps[e]) * 0.015625f;
    }
}

// One wave per WG, 16 rows per wave, double-buffered LDS (2 x 16 KB).
// Grid 1024 = 4 WG/CU, all co-resident (no residency batching tail).
// Per-row issue order (in-order vmcnt retirement):
//   [S2(16) U(16)] [glds_{r+1}(16) -> other buf] WAIT vmcnt(16)
//   -> waits: row-r glds + prev stores + S2 + U; keeps glds_{r+1} in
//      flight for the ENTIRE row (full-row latency cover). No other
//      vmem consumer can drain it: S1 is persistent (prologue), S2/U
//      retire at the counted wait, stores have no consumers.
__global__ __launch_bounds__(64, 2) void whvi_kernel(const float* __restrict__ x,
                                                     const float* __restrict__ s1,
                                                     const float* __restrict__ s2,
                                                     const float* __restrict__ u_perm,
                                                     float* __restrict__ out,
                                                     int nrows) {
    __shared__ float lds[2 * D_DIM];
    const int l = threadIdx.x;
    const int l4 = l << 2;
    const int L4 = (l & 15) << 2;
    const int row0 = blockIdx.x * ROWS_PER_WG;
    const int rend = min(row0 + ROWS_PER_WG, nrows);
    const unsigned ldsbase = (unsigned)(uintptr_t)(&lds[0]);

    // ---- prologue: prefetch row0 into buffer 0 (oldest vmem ops) ----
    {
        const float* xr = x + (size_t)row0 * D_DIM;
#pragma unroll
        for (int k = 0; k < 16; ++k) gload_lds16(xr + (k << 8) + l4, &lds[k << 8]);
    }
    __builtin_amdgcn_sched_barrier(0);

    // ---- persistent S1 (constant across rows; loaded once, after glds) ----
    float4 S1[16];
#pragma unroll
    for (int k = 0; k < 16; ++k) S1[k] = *reinterpret_cast<const float4*>(s1 + (k << 8) + l4);

    v2f w[32];

    for (int row = row0; row < rend; ++row) {
        const unsigned bc = ldsbase + ((row & 1) ? (unsigned)(D_DIM * 4) : 0u);
        float* bufn = &lds[(row & 1) ? 0 : D_DIM];

        // ---- per-row scale loads (L2-resident), BEFORE the prefetch ----
        const float* s2p = launder_ptr(s2);
        float4 S2[16];
#pragma unroll
        for (int k = 0; k < 16; ++k) S2[k] = *reinterpret_cast<const float4*>(s2p + (k << 8) + l4);
        const float* upp = launder_ptr(u_perm);
        float4 U[16];
#pragma unroll
        for (int k = 0; k < 16; ++k) U[k] = *reinterpret_cast<const float4*>(upp + (l << 6) + (k << 2));
        __builtin_amdgcn_sched_barrier(0);

        // ---- full next-row prefetch at TOP of the row (max cover) ----
        if (row + 1 < rend) {
            const float* xn = x + (size_t)(row + 1) * D_DIM;
#pragma unroll
            for (int k = 0; k < 16; ++k) gload_lds16(xn + (k << 8) + l4, bufn + (k << 8));
        }
        __builtin_amdgcn_sched_barrier(0);

        // waits row-r glds + S2 + U + prev stores; keeps glds_{r+1} in flight
        asm volatile("s_waitcnt vmcnt(16)" ::: "memory");
        __builtin_amdgcn_sched_barrier(0);

        // ---- phase A: x (linear LDS) * s2, FWHT bits {0,1,8..11} ----
        {
            float4 X[8];
#pragma unroll
            for (int k = 0; k < 8; ++k) X[k] = ds_read128(bc + (unsigned)((k << 10) + (l << 4)));
            wait_lgkm0();
#pragma unroll
            for (int k = 0; k < 8; ++k) {
                w[2 * k]     = pkmul((v2f){X[k].x, X[k].y}, (v2f){S2[k].x, S2[k].y});
                w[2 * k + 1] = pkmul((v2f){X[k].z, X[k].w}, (v2f){S2[k].z, S2[k].w});
            }
#pragma unroll
            for (int k = 0; k < 8; ++k) X[k] = ds_read128(bc + (unsigned)(((k + 8) << 10) + (l << 4)));
            wait_lgkm0();
#pragma unroll
            for (int k = 0; k < 8; ++k) {
                w[2 * (k + 8)]     = pkmul((v2f){X[k].x, X[k].y}, (v2f){S2[k + 8].x, S2[k + 8].y});
                w[2 * (k + 8) + 1] = pkmul((v2f){X[k].z, X[k].w}, (v2f){S2[k + 8].z, S2[k + 8].w});
            }
        }
        radix64(w);

        // ---- T1: scatter writes, word = (v<<6) + (l ^ ((v&15)<<2)) ----
#pragma unroll
        for (int v = 0; v < 64; ++v) {
            const unsigned a = bc + (unsigned)((((v << 6) + (l ^ ((v & 15) << 2))) << 2));
            ds_write32(a, (v & 1) ? w[v >> 1].y : w[v >> 1].x);
        }
        wait_lgkm0();

        // ---- phase B: swizzled b128 reads, FWHT bits {2..7}, *u, FWHT ----
        {
            float4 F[16];
#pragma unroll
            for (int k = 0; k < 16; ++k) {
                const unsigned a = bc + (unsigned)(((l << 6) + ((k << 2) ^ L4)) << 2);
                F[k] = ds_read128(a);
            }
            wait_lgkm0();
#pragma unroll
            for (int k = 0; k < 16; ++k) {
                w[2 * k]     = (v2f){F[k].x, F[k].y};
                w[2 * k + 1] = (v2f){F[k].z, F[k].w};
            }
        }
        radix64(w);
#pragma unroll
        for (int k = 0; k < 16; ++k) {
            w[2 * k]     = pkmul(w[2 * k],     (v2f){U[k].x, U[k].y});
            w[2 * k + 1] = pkmul(w[2 * k + 1], (v2f){U[k].z, U[k].w});
        }
        radix64(w);

        // ---- T2 ----
#pragma unroll
        for (int m = 0; m < 64; ++m) {
            const unsigned a = bc + (unsigned)((((m << 6) + (l ^ ((m & 15) << 2))) << 2));
            ds_write32(a, (m & 1) ? w[m >> 1].y : w[m >> 1].x);
        }
        wait_lgkm0();

        // ---- phase A': swizzled b128 reads, FWHT bits {0,1,8..11} ----
        {
            float4 F[16];
#pragma unroll
            for (int k = 0; k < 16; ++k) {
                const unsigned a = bc + (unsigned)(((l << 6) + ((k << 2) ^ L4)) << 2);
                F[k] = ds_read128(a);
            }
            wait_lgkm0();
#pragma unroll
            for (int k = 0; k < 16; ++k) {
                w[2 * k]     = (v2f){F[k].x, F[k].y};
                w[2 * k + 1] = (v2f){F[k].z, F[k].w};
            }
        }
        radix64(w);

        // ---- scale by persistent S1, plain coalesced float4 stores ----
        float* orow = out + (size_t)row * D_DIM;
#pragma unroll
        for (int r = 0; r < 16; ++r) {
            const v2f o0 = pkmul(w[2 * r],     (v2f){S1[r].x, S1[r].y});
            const v2f o1 = pkmul(w[2 * r + 1], (v2f){S1[r].z, S1[r].w});
            *reinterpret_cast<float4*>(orow + (r << 8) + l4) =
                make_float4(o0.x, o0.y, o1.x, o1.y);
        }
    }
}

extern "C" void kernel_launch(void* const* d_in, const int* in_sizes, int n_in,
                              void* d_out, int out_size, void* d_ws, size_t ws_size,
                              hipStream_t stream) {
    const float* x     = (const float*)d_in[0];
    const float* s1    = (const float*)d_in[1];
    const float* s2    = (const float*)d_in[2];
    const float* g_mu  = (const float*)d_in[3];
    const float* g_rho = (const float*)d_in[4];
    const float* eps   = (const float*)d_in[5];
    // d_in[6] = H : realized implicitly by the FWHT butterflies.

    float* u_perm = (float*)d_ws;
    float* out    = (float*)d_out;

    const int N = in_sizes[0] / D_DIM;
    const int nwg = (N + ROWS_PER_WG - 1) / ROWS_PER_WG;

    compute_u_kernel<<<(D_DIM + 255) / 256, 256, 0, stream>>>(g_mu, g_rho, eps, u_perm);
    whvi_kernel<<<nwg, 64, 0, stream>>>(x, s1, s2, u_perm, out, N);
}

// Round 8
// 212.504 us; speedup vs baseline: 2.0414x; 2.0414x over previous
//
#include <hip/hip_runtime.h>
#include <math.h>

#define D_DIM 4096

typedef float v2f __attribute__((ext_vector_type(2)));

// ---- packed-f32 butterfly primitives (VOP3P) ----
__device__ __forceinline__ v2f bfly0(v2f a) {
    v2f d;
    asm("v_pk_add_f32 %0, %1, %2 op_sel:[0,1] op_sel_hi:[0,1] neg_hi:[0,1]"
        : "=v"(d) : "v"(a), "v"(a));
    return d;
}
__device__ __forceinline__ v2f pkadd(v2f a, v2f b) {
    v2f d; asm("v_pk_add_f32 %0, %1, %2" : "=v"(d) : "v"(a), "v"(b)); return d;
}
__device__ __forceinline__ v2f pksub(v2f a, v2f b) {
    v2f d; asm("v_pk_add_f32 %0, %1, %2 neg_lo:[0,1] neg_hi:[0,1]" : "=v"(d) : "v"(a), "v"(b)); return d;
}
__device__ __forceinline__ v2f pkmul(v2f a, v2f b) {
    v2f d; asm("v_pk_mul_f32 %0, %1, %2" : "=v"(d) : "v"(a), "v"(b)); return d;
}

// In-register FWHT over 6 bits: 64 values as 32 packed v2f.
__device__ __forceinline__ void radix64(v2f w[32]) {
#pragma unroll
    for (int p = 0; p < 32; ++p) w[p] = bfly0(w[p]);
#pragma unroll
    for (int s = 0; s < 5; ++s) {
        const int d = 1 << s;
#pragma unroll
        for (int p = 0; p < 32; ++p) {
            if (!(p & d)) {
                const v2f a = w[p];
                const v2f b = w[p + d];
                w[p]     = pkadd(a, b);
                w[p + d] = pksub(a, b);
            }
        }
    }
}

// u_perm[l*64 + m] = u[e]/64, e = (l>>2)*256 + m*4 + (l&3)  (B-layout).
__global__ void compute_u_kernel(const float* __restrict__ g_mu,
                                 const float* __restrict__ g_rho,
                                 const float* __restrict__ eps,
                                 float* __restrict__ u_perm) {
    const int j = blockIdx.x * blockDim.x + threadIdx.x;
    if (j < D_DIM) {
        const int e = ((j >> 8) << 8) | ((j & 63) << 2) | ((j >> 6) & 3);
        const float r = g_rho[e];
        const float sp = (r > 20.0f) ? r : log1pf(expf(r));
        u_perm[j] = (g_mu[e] + sp * eps[e]) * 0.015625f;
    }
}

// One row per 64-thread (1-wave) WG, LDS = 8 KB (occupancy play: 160/8 = 20
// WGs/CU possible; VGPR is the expected cap at ~16 waves/CU).
// The 64x64 lane<->reg transpose is done in TWO half-stages of 8 KB each:
//   stage v in [32,64): all lanes write those 32 values; lanes l'>=32 (which
//   need v = l') read their full row of 64; then stage v in [0,32) for l'<32.
// Reads land in a fresh array so the not-yet-staged half of the source regs
// survives (peak live = 32 old + 64 new = 96 VGPRs).
__global__ __launch_bounds__(64, 4) void whvi_kernel(const float* __restrict__ x,
                                                     const float* __restrict__ s1,
                                                     const float* __restrict__ s2,
                                                     const float* __restrict__ u_perm,
                                                     float* __restrict__ out) {
    __shared__ float lds[2048];  // 8 KB
    const int l = threadIdx.x;
    const int l4 = l << 2;
    const int L4 = (l & 15) << 2;
    const int row = blockIdx.x;
    const float* __restrict__ xr = x + (size_t)row * D_DIM;

    v2f w[32];

    // ---- phase A: coalesced b128 loads of x and s2, FWHT bits {0,1,8..11} ----
#pragma unroll
    for (int k = 0; k < 16; ++k) {
        const int off = (k << 8) + l4;  // e = 256k + 4l + q
        const float4 xv = *reinterpret_cast<const float4*>(xr + off);
        const float4 sv = *reinterpret_cast<const float4*>(s2 + off);
        w[2 * k]     = pkmul((v2f){xv.x, xv.y}, (v2f){sv.x, sv.y});
        w[2 * k + 1] = pkmul((v2f){xv.z, xv.w}, (v2f){sv.z, sv.w});
    }
    radix64(w);

    v2f nw[32];

    // ---- T1, half 0: stage v in [32,64); readers are lanes l >= 32 ----
#pragma unroll
    for (int v = 32; v < 64; ++v)
        lds[((v & 31) << 6) + (l ^ ((v & 15) << 2))] = (v & 1) ? w[v >> 1].y : w[v >> 1].x;
    __syncthreads();
    if (l >= 32) {
#pragma unroll
        for (int k = 0; k < 16; ++k) {
            const float4 f = *reinterpret_cast<const float4*>(&lds[((l & 31) << 6) + ((k << 2) ^ L4)]);
            nw[2 * k]     = (v2f){f.x, f.y};
            nw[2 * k + 1] = (v2f){f.z, f.w};
        }
    }
    __syncthreads();

    // ---- T1, half 1: stage v in [0,32); readers are lanes l < 32 ----
#pragma unroll
    for (int v = 0; v < 32; ++v)
        lds[((v & 31) << 6) + (l ^ ((v & 15) << 2))] = (v & 1) ? w[v >> 1].y : w[v >> 1].x;
    __syncthreads();
    if (l < 32) {
#pragma unroll
        for (int k = 0; k < 16; ++k) {
            const float4 f = *reinterpret_cast<const float4*>(&lds[((l & 31) << 6) + ((k << 2) ^ L4)]);
            nw[2 * k]     = (v2f){f.x, f.y};
            nw[2 * k + 1] = (v2f){f.z, f.w};
        }
    }
    __syncthreads();

    // ---- phase B: FWHT bits {2..7}, * u, FWHT bits {2..7} ----
    radix64(nw);
#pragma unroll
    for (int k = 0; k < 16; ++k) {
        const float4 uv = *reinterpret_cast<const float4*>(u_perm + (l << 6) + (k << 2));
        nw[2 * k]     = pkmul(nw[2 * k],     (v2f){uv.x, uv.y});
        nw[2 * k + 1] = pkmul(nw[2 * k + 1], (v2f){uv.z, uv.w});
    }
    radix64(nw);

    // ---- T2, half 0: stage m in [32,64); readers l >= 32 ----
#pragma unroll
    for (int m = 32; m < 64; ++m)
        lds[((m & 31) << 6) + (l ^ ((m & 15) << 2))] = (m & 1) ? nw[m >> 1].y : nw[m >> 1].x;
    __syncthreads();
    if (l >= 32) {
#pragma unroll
        for (int k = 0; k < 16; ++k) {
            const float4 f = *reinterpret_cast<const float4*>(&lds[((l & 31) << 6) + ((k << 2) ^ L4)]);
            w[2 * k]     = (v2f){f.x, f.y};
            w[2 * k + 1] = (v2f){f.z, f.w};
        }
    }
    __syncthreads();

    // ---- T2, half 1: stage m in [0,32); readers l < 32 ----
#pragma unroll
    for (int m = 0; m < 32; ++m)
        lds[((m & 31) << 6) + (l ^ ((m & 15) << 2))] = (m & 1) ? nw[m >> 1].y : nw[m >> 1].x;
    __syncthreads();
    if (l < 32) {
#pragma unroll
        for (int k = 0; k < 16; ++k) {
            const float4 f = *reinterpret_cast<const float4*>(&lds[((l & 31) << 6) + ((k << 2) ^ L4)]);
            w[2 * k]     = (v2f){f.x, f.y};
            w[2 * k + 1] = (v2f){f.z, f.w};
        }
    }

    // ---- phase A': FWHT bits {0,1,8..11}, * s1, coalesced store ----
    radix64(w);
    float* __restrict__ orow = out + (size_t)row * D_DIM;
#pragma unroll
    for (int r = 0; r < 16; ++r) {
        const int off = (r << 8) + l4;
        const float4 sv = *reinterpret_cast<const float4*>(s1 + off);
        const v2f o0 = pkmul(w[2 * r],     (v2f){sv.x, sv.y});
        const v2f o1 = pkmul(w[2 * r + 1], (v2f){sv.z, sv.w});
        *reinterpret_cast<float4*>(orow + off) = make_float4(o0.x, o0.y, o1.x, o1.y);
    }
}

extern "C" void kernel_launch(void* const* d_in, const int* in_sizes, int n_in,
                              void* d_out, int out_size, void* d_ws, size_t ws_size,
                              hipStream_t stream) {
    const float* x     = (const float*)d_in[0];
    const float* s1    = (const float*)d_in[1];
    const float* s2    = (const float*)d_in[2];
    const float* g_mu  = (const float*)d_in[3];
    const float* g_rho = (const float*)d_in[4];
    const float* eps   = (const float*)d_in[5];
    // d_in[6] = H : realized implicitly by the FWHT butterflies.

    float* u_perm = (float*)d_ws;
    float* out    = (float*)d_out;

    const int N = in_sizes[0] / D_DIM;

    compute_u_kernel<<<(D_DIM + 255) / 256, 256, 0, stream>>>(g_mu, g_rho, eps, u_perm);
    whvi_kernel<<<N, 64, 0, stream>>>(x, s1, s2, u_perm, out);
}